// Round 7
// baseline (54.982 us; speedup 1.0000x reference)
//
#include <hip/hip_runtime.h>
#include <hip/hip_fp8.h>
#include <stdint.h>

#define MARGIN 0.3f
#define NROWS 4096
#define DIM   2048
#define BT    128
#define BK    128                   // fp8 K-elements (= bytes) per tile row
#define NK    (DIM / BK)            // 16
#define NB    (NROWS / BT)          // 32
#define NBLK  (NB * (NB + 1) / 2)   // 528 (divisible by 8 -> clean XCD swizzle)

typedef float f32x4 __attribute__((ext_vector_type(4)));
typedef int   i32x4 __attribute__((ext_vector_type(4)));
typedef int   i32x8 __attribute__((ext_vector_type(8)));
typedef short s16x8 __attribute__((ext_vector_type(8)));

__device__ __forceinline__ unsigned char f32_to_fp8(float f) {
  __hip_fp8_e4m3 h(f);                 // OCP e4m3fn on gfx950
  return (unsigned char)h.__x;
}

__device__ __forceinline__ ushort f32_to_bf16(float f) {
  uint32_t u = __float_as_uint(f);
  return (ushort)((u + 0x7FFFu + ((u >> 16) & 1u)) >> 16);
}

// async global->LDS, 16B per lane. LDS dest is wave-uniform base + lane*16
// (linear). The k-slot XOR swizzle is carried on the GLOBAL source address.
__device__ __forceinline__ void async_load16(const void* g, void* l) {
  __builtin_amdgcn_global_load_lds(
      (const __attribute__((address_space(1))) uint32_t*)g,
      (__attribute__((address_space(3))) uint32_t*)l, 16, 0, 0);
}

// ---------------------------------------------------------------------------
// prep: row L2-norm. FLY=0: write normalized fp8(e4m3) matrix. FLY=1: 1/norm.
// Also zeroes the accumulators.
// ---------------------------------------------------------------------------
template <int FLY>
__global__ __launch_bounds__(256) void prep_kernel(const float* __restrict__ in,
                                                   unsigned char* __restrict__ pn,
                                                   float* __restrict__ invn,
                                                   float* __restrict__ accum) {
  const int row = blockIdx.x;
  const int tid = threadIdx.x;
  if (row == 0 && tid == 0) { accum[0] = 0.f; accum[1] = 0.f; }

  const float4* rp = (const float4*)(in + (size_t)row * DIM);
  float4 v0 = rp[tid * 2];
  float4 v1 = rp[tid * 2 + 1];
  float ss = v0.x*v0.x + v0.y*v0.y + v0.z*v0.z + v0.w*v0.w
           + v1.x*v1.x + v1.y*v1.y + v1.z*v1.z + v1.w*v1.w;
  #pragma unroll
  for (int off = 32; off; off >>= 1) ss += __shfl_down(ss, off);

  __shared__ float wred[4];
  __shared__ float stot;
  const int lane = tid & 63, w = tid >> 6;
  if (lane == 0) wred[w] = ss;
  __syncthreads();
  if (tid == 0) stot = wred[0] + wred[1] + wred[2] + wred[3];
  __syncthreads();
  const float inv = 1.0f / fmaxf(sqrtf(stot), 1e-12f);

  if (FLY) {
    if (tid == 0) invn[row] = inv;
  } else {
    union { unsigned char b[8]; uint2 u; } pack;
    pack.b[0] = f32_to_fp8(v0.x * inv); pack.b[1] = f32_to_fp8(v0.y * inv);
    pack.b[2] = f32_to_fp8(v0.z * inv); pack.b[3] = f32_to_fp8(v0.w * inv);
    pack.b[4] = f32_to_fp8(v1.x * inv); pack.b[5] = f32_to_fp8(v1.y * inv);
    pack.b[6] = f32_to_fp8(v1.z * inv); pack.b[7] = f32_to_fp8(v1.w * inv);
    *(uint2*)(pn + (size_t)row * DIM + tid * 8) = pack.u;
  }
}

// ---------------------------------------------------------------------------
// tri_gemm: one block per upper-triangular 128x128 super-tile of sim = Pn Pn^T.
// fp8 e4m3 via mfma_scale_f32_16x16x128_f8f6f4 with all scales = 1.0 (0x7F).
// 256 threads = 4 waves (2x2), wave tile 64x64 (4x4 frags), BK=128, 16 steps.
// MINIMUM 2-PHASE PIPELINE (catalog T3 recipe, no inline asm):
//   prologue: stage(buf0); __syncthreads();
//   step ks : stage(next into buf^1) -> ds_read+MFMA from buf -> __syncthreads
// The end-of-step __syncthreads' implicit vmcnt(0) waits for loads issued at
// the START of the step, so HBM/L2 latency hides under ds_read+MFMA.
// Hazard: buf overwritten at step t+1 was read at step t; those ds_reads are
// lgkm-drained before t's MFMA and fenced by t's barrier -> safe.
// ---------------------------------------------------------------------------
__global__ __launch_bounds__(256) void tri_gemm(const unsigned char* __restrict__ pn,
                                                float* __restrict__ accum) {
  // XCD-aware bijective swizzle (NBLK % 8 == 0): consecutive tiles (sharing
  // the A-panel) land on the same XCD's L2.
  const int b = blockIdx.x;
  int t = (b & 7) * (NBLK / 8) + (b >> 3);
  int bi = 0;
  while (t >= NB - bi) { t -= NB - bi; ++bi; }
  const int bj = bi + t;

  __shared__ __align__(16) unsigned char Asm[2][BT * BK];   // 2 x 16 KB
  __shared__ __align__(16) unsigned char Bsm[2][BT * BK];   // 2 x 16 KB

  const int tid  = threadIdx.x;
  const int lane = tid & 63;
  const int w    = tid >> 6;          // 0..3
  const int wr   = w >> 1;            // 0..1  (64-row band of A)
  const int wc   = w & 1;             // 0..1  (64-row band of B)

  f32x4 acc[4][4] = {};
  const int rowA = bi * BT, rowB = bj * BT;

  // staging: 1 KB chunk = 8 rows x 128 B; lane l -> row +(l>>3), stored slot
  // (l&7); global true-k slot = (l&7) ^ (l>>3)
  const int srow  = (lane >> 3);
  const int gslot = (lane & 7) ^ srow;

  const unsigned char* gA = pn + (size_t)(rowA + srow) * DIM + gslot * 16;
  const unsigned char* gB = pn + (size_t)(rowB + srow) * DIM + gslot * 16;

  unsigned char* Acur = Asm[0];  unsigned char* Bcur = Bsm[0];
  unsigned char* Anx  = Asm[1];  unsigned char* Bnx  = Bsm[1];

  // prologue: stage K-step 0
  #pragma unroll
  for (int q = 0; q < 4; ++q) {
    const int r = w * 32 + q * 8;
    async_load16(gA + (size_t)r * DIM, Acur + r * BK);
    async_load16(gB + (size_t)r * DIM, Bcur + r * BK);
  }
  __syncthreads();   // vmcnt(0) drain + barrier: buf0 ready

  const int fr = lane & 15, g = lane >> 4;

  #pragma unroll 1
  for (int ks = 0; ks < NK; ++ks) {
    // 1) issue next tile's loads FIRST (latency overlaps this step's compute)
    if (ks + 1 < NK) {
      const int k0 = (ks + 1) * BK;
      #pragma unroll
      for (int q = 0; q < 4; ++q) {
        const int r = w * 32 + q * 8;
        async_load16(gA + (size_t)r * DIM + k0, Anx + r * BK);
        async_load16(gB + (size_t)r * DIM + k0, Bnx + r * BK);
      }
    }

    // 2) fragments from current buffer: lane -> row (l&15), k-group g=(l>>4)
    //    bytes [g*32, g*32+32) = stored 16B slots (2g)^(row&7), (2g+1)^(row&7)
    i32x8 af[4], bfv[4];
    #pragma unroll
    for (int m = 0; m < 4; ++m) {
      const int ra = wr * 64 + m * 16 + fr;
      const unsigned char* base = Acur + ra * BK;
      i32x4 lo = *(const i32x4*)(base + ((2 * g)     ^ (ra & 7)) * 16);
      i32x4 hi = *(const i32x4*)(base + ((2 * g + 1) ^ (ra & 7)) * 16);
      af[m] = __builtin_shufflevector(lo, hi, 0, 1, 2, 3, 4, 5, 6, 7);
    }
    #pragma unroll
    for (int n = 0; n < 4; ++n) {
      const int rb = wc * 64 + n * 16 + fr;
      const unsigned char* base = Bcur + rb * BK;
      i32x4 lo = *(const i32x4*)(base + ((2 * g)     ^ (rb & 7)) * 16);
      i32x4 hi = *(const i32x4*)(base + ((2 * g + 1) ^ (rb & 7)) * 16);
      bfv[n] = __builtin_shufflevector(lo, hi, 0, 1, 2, 3, 4, 5, 6, 7);
    }

    #pragma unroll
    for (int m = 0; m < 4; ++m)
      #pragma unroll
      for (int n = 0; n < 4; ++n)
        acc[m][n] = __builtin_amdgcn_mfma_scale_f32_16x16x128_f8f6f4(
            af[m], bfv[n], acc[m][n],
            0, 0,                      // cbsz=fp8(e4m3), blgp=fp8(e4m3)
            0, 0x7F7F7F7F,             // scale_a: all e8m0 bytes = 1.0
            0, 0x7F7F7F7F);            // scale_b: all e8m0 bytes = 1.0

    // 3) single drain+barrier per step: waits for loads issued in (1),
    //    which had the whole ds_read+MFMA phase to complete.
    __syncthreads();

    unsigned char* tp;
    tp = Acur; Acur = Anx; Anx = tp;
    tp = Bcur; Bcur = Bnx; Bnx = tp;
  }

  // ---- epilogue: mask + reduce (C/D layout is shape-determined) ----
  float lsum = 0.f, lcnt = 0.f;
  const int gib = rowA + wr * 64;
  const int gjb = rowB + wc * 64;
  #pragma unroll
  for (int m = 0; m < 4; ++m) {
    #pragma unroll
    for (int n = 0; n < 4; ++n) {
      #pragma unroll
      for (int r = 0; r < 4; ++r) {
        int gi = gib + m * 16 + (lane >> 4) * 4 + r;
        int gj = gjb + n * 16 + (lane & 15);
        float s = acc[m][n][r];
        if (gi < gj && s > MARGIN) { lsum += s - MARGIN; lcnt += 1.f; }
      }
    }
  }
  #pragma unroll
  for (int off = 32; off; off >>= 1) {
    lsum += __shfl_down(lsum, off);
    lcnt += __shfl_down(lcnt, off);
  }
  __shared__ float rs[4], rc[4];
  if (lane == 0) { rs[w] = lsum; rc[w] = lcnt; }
  __syncthreads();
  if (tid == 0) {
    atomicAdd(&accum[0], rs[0] + rs[1] + rs[2] + rs[3]);
    atomicAdd(&accum[1], rc[0] + rc[1] + rc[2] + rc[3]);
  }
}

// ---------------------------------------------------------------------------
// Fallback (tiny workspace): bf16 on-the-fly convert, 256 threads / 4 waves,
// single-buffer, BK=64 bf16 (verified R2 structure).
// ---------------------------------------------------------------------------
__global__ __launch_bounds__(256) void tri_gemm_fly(const float* __restrict__ inF,
                                                    const float* __restrict__ invn,
                                                    float* __restrict__ accum) {
  enum { FBK = 64 };
  int t = blockIdx.x, bi = 0;
  while (t >= NB - bi) { t -= NB - bi; ++bi; }
  const int bj = bi + t;

  __shared__ __align__(16) ushort Asm[BT * FBK];
  __shared__ __align__(16) ushort Bsm[BT * FBK];

  const int tid  = threadIdx.x;
  const int lane = tid & 63;
  const int w    = tid >> 6;
  const int wr   = w >> 1, wc = w & 1;

  f32x4 acc[4][4] = {};
  const int rowA = bi * BT, rowB = bj * BT;

  for (int k0 = 0; k0 < DIM; k0 += FBK) {
    if (k0) __syncthreads();
    #pragma unroll
    for (int p = 0; p < 8; ++p) {
      int c   = p * 256 + tid;
      int isB = c >> 10;
      int cc  = c & 1023;
      int r   = cc >> 3;
      int s   = cc & 7;
      const int grow = (isB ? rowB : rowA) + r;
      const float4* src = (const float4*)(inF + (size_t)grow * DIM + k0 + s * 8);
      float4 v0 = src[0], v1 = src[1];
      int4 pack;
      ushort* h = (ushort*)&pack;
      h[0] = f32_to_bf16(v0.x); h[1] = f32_to_bf16(v0.y);
      h[2] = f32_to_bf16(v0.z); h[3] = f32_to_bf16(v0.w);
      h[4] = f32_to_bf16(v1.x); h[5] = f32_to_bf16(v1.y);
      h[6] = f32_to_bf16(v1.z); h[7] = f32_to_bf16(v1.w);
      *(int4*)((isB ? Bsm : Asm) + r * FBK + (s ^ (r & 7)) * 8) = pack;
    }
    __syncthreads();

    s16x8 af[2][4], bfv[2][4];
    const int fr = lane & 15, hi = lane >> 4;
    #pragma unroll
    for (int kk = 0; kk < 2; ++kk)
      #pragma unroll
      for (int m = 0; m < 4; ++m) {
        const int ra = wr * 64 + m * 16 + fr;
        af[kk][m] = *(const s16x8*)(Asm + ra * FBK + ((kk * 4 + hi) ^ (ra & 7)) * 8);
        const int rb = wc * 64 + m * 16 + fr;
        bfv[kk][m] = *(const s16x8*)(Bsm + rb * FBK + ((kk * 4 + hi) ^ (rb & 7)) * 8);
      }
    #pragma unroll
    for (int kk = 0; kk < 2; ++kk)
      #pragma unroll
      for (int m = 0; m < 4; ++m)
        #pragma unroll
        for (int n = 0; n < 4; ++n)
          acc[m][n] = __builtin_amdgcn_mfma_f32_16x16x32_bf16(af[kk][m], bfv[kk][n],
                                                              acc[m][n], 0, 0, 0);
  }

  float lsum = 0.f, lcnt = 0.f;
  const int gib = rowA + wr * 64;
  const int gjb = rowB + wc * 64;
  #pragma unroll
  for (int m = 0; m < 4; ++m)
    #pragma unroll
    for (int n = 0; n < 4; ++n)
      #pragma unroll
      for (int r = 0; r < 4; ++r) {
        int gi = gib + m * 16 + (lane >> 4) * 4 + r;
        int gj = gjb + n * 16 + (lane & 15);
        float s = acc[m][n][r] * invn[gi] * invn[gj];
        if (gi < gj && s > MARGIN) { lsum += s - MARGIN; lcnt += 1.f; }
      }
  #pragma unroll
  for (int off = 32; off; off >>= 1) {
    lsum += __shfl_down(lsum, off);
    lcnt += __shfl_down(lcnt, off);
  }
  __shared__ float rs[4], rc[4];
  if (lane == 0) { rs[w] = lsum; rc[w] = lcnt; }
  __syncthreads();
  if (tid == 0) {
    atomicAdd(&accum[0], rs[0] + rs[1] + rs[2] + rs[3]);
    atomicAdd(&accum[1], rc[0] + rc[1] + rc[2] + rc[3]);
  }
}

__global__ void finalize_kernel(const float* __restrict__ accum, float* __restrict__ out) {
  if (threadIdx.x == 0) out[0] = (accum[1] < 0.5f) ? 0.0f : accum[0] / accum[1];
}

extern "C" void kernel_launch(void* const* d_in, const int* in_sizes, int n_in,
                              void* d_out, int out_size, void* d_ws, size_t ws_size,
                              hipStream_t stream) {
  const float* in = (const float*)d_in[0];
  float* out = (float*)d_out;
  const size_t pn_bytes = (size_t)NROWS * DIM;   // fp8: 8.4 MB

  if (ws_size >= pn_bytes + 2 * sizeof(float)) {
    unsigned char* pn = (unsigned char*)d_ws;
    float* accum = (float*)((char*)d_ws + pn_bytes);
    prep_kernel<0><<<NROWS, 256, 0, stream>>>(in, pn, nullptr, accum);
    tri_gemm<<<NBLK, 256, 0, stream>>>(pn, accum);
    finalize_kernel<<<1, 64, 0, stream>>>(accum, out);
  } else {
    float* invn  = (float*)d_ws;
    float* accum = (float*)((char*)d_ws + NROWS * sizeof(float));
    prep_kernel<1><<<NROWS, 256, 0, stream>>>(in, nullptr, invn, accum);
    tri_gemm_fly<<<NBLK, 256, 0, stream>>>(in, invn, accum);
    finalize_kernel<<<1, 64, 0, stream>>>(accum, out);
  }
}